// Round 7
// baseline (304.764 us; speedup 1.0000x reference)
//
#include <hip/hip_runtime.h>
#include <stdint.h>

// ProposalLayer: top-6000 select -> bbox regression+clip -> greedy NMS -> 2000 proposals
// B=8, N=261888, all float32.

#define BATCH   8
#define NN      261888
#define PRE_NMS 6000
#define NUM_PROP 2000
#define CAND_CAP 8192
#define STASH_CAP 32768    // in-bin elements per batch; uniform scores -> ~N/16=16.4K, 2x margin
#define EDGE_CAP 16384
#define NTILE   94         // ceil(6000/64)
#define NPAD    6016       // NTILE*64
#define NW32    188

// workspace layout (bytes)
#define OFF_HIST1  4096
#define OFF_HIST2  (OFF_HIST1 + BATCH*4096*4)
#define OFF_KEY    (OFF_HIST2 + BATCH*4096*4)          // memset covers [0, OFF_KEY)
#define OFF_SORTED (OFF_KEY + BATCH*CAND_CAP*8)
#define OFF_BOXES  (OFF_SORTED + BATCH*PRE_NMS*4)
#define OFF_AREAS  (OFF_BOXES + BATCH*NPAD*16)
#define OFF_EDGES  (OFF_AREAS + BATCH*NPAD*4)
#define WS_NEED    (OFF_EDGES + BATCH*EDGE_CAP*4)      // ~2.47 MB
// stash (u32 indices, 1MB) aliases boxes+areas+edges head: written in k_hist2c,
// read in k_compact2, both BEFORE k_gather/k_edges write those regions.
#define OFF_STASH  OFF_BOXES

// state u32 indices: [b]=L1 bin, [8+b]=Krem, [16+b]=threshold.
// Counters spread 128B (32 u32) apart: one cache line per batch.
#define CNT_KEY(b)   (64  + (b)*32)
#define CNT_EDGE(b)  (320 + (b)*32)
#define CNT_STASH(b) (576 + (b)*32)

__device__ __forceinline__ uint32_t fkey(float s){
  uint32_t b = __float_as_uint(s);
  return (b & 0x80000000u) ? ~b : (b | 0x80000000u);   // order-preserving float->u32
}

__device__ __forceinline__ uint64_t shfl64(uint64_t v, int src){
  uint32_t lo = __shfl((uint32_t)(v & 0xFFFFFFFFull), src, 64);
  uint32_t hi = __shfl((uint32_t)(v >> 32), src, 64);
  return (uint64_t)lo | ((uint64_t)hi << 32);
}

// wave-aggregated counter reservation: one atomic per wave instead of per lane.
__device__ __forceinline__ uint32_t wave_reserve(bool pred, uint32_t* ctr){
  uint64_t m = __ballot((int)pred);
  if (!m) return 0xFFFFFFFFu;
  int lane = (int)(threadIdx.x & 63u);
  int leader = __ffsll((unsigned long long)m) - 1;
  uint32_t base = 0;
  if (lane == leader) base = atomicAdd(ctr, (uint32_t)__popcll(m));
  base = __shfl(base, leader, 64);
  return base + (uint32_t)__popcll(m & ((1ull << lane) - 1ull));
}

// ---- level-1 histogram of top 12 bits of fkey ----
__global__ void k_hist1(const float* __restrict__ probs, char* ws){
  __shared__ uint32_t h[4096];
  int b = blockIdx.y;
  for (int t = threadIdx.x; t < 4096; t += 256) h[t] = 0;
  __syncthreads();
  const float2* p2 = (const float2*)probs + (size_t)b * NN;
  int base = blockIdx.x * 2048;
  for (int k = 0; k < 8; ++k){
    int i = base + k*256 + threadIdx.x;
    if (i < NN) atomicAdd(&h[fkey(p2[i].y) >> 20], 1u);
  }
  __syncthreads();
  uint32_t* gh = (uint32_t*)(ws + OFF_HIST1) + b*4096;
  for (int t = threadIdx.x; t < 4096; t += 256) if (h[t]) atomicAdd(&gh[t], h[t]);
}

// ---- find histogram bin where cumulative-from-top crosses K ----
__global__ void k_resolve(char* ws, int level){
  uint32_t* state = (uint32_t*)ws;
  const uint32_t* gh = (const uint32_t*)(ws + (level == 1 ? OFF_HIST1 : OFF_HIST2)) + blockIdx.x*4096;
  __shared__ uint32_t part[256];
  int b = blockIdx.x, t = threadIdx.x;
  uint32_t s = 0;
  for (int k = 0; k < 16; ++k) s += gh[t*16 + k];
  part[t] = s;
  __syncthreads();
  if (t == 0){
    uint32_t K = (level == 1) ? (uint32_t)PRE_NMS : state[8 + b];
    uint32_t cum = 0; int c = 255;
    for (; c > 0; --c){ if (cum + part[c] >= K) break; cum += part[c]; }
    uint32_t rem = K - cum;
    uint32_t cum2 = 0; int bin = c*16;
    for (int k = 15; k >= 0; --k){
      uint32_t v = gh[c*16 + k];
      if (cum2 + v >= rem){ bin = c*16 + k; rem = rem - cum2; break; }
      cum2 += v;
    }
    if (level == 1){ state[b] = (uint32_t)bin; state[8 + b] = rem; }
    else           { state[16 + b] = (state[b] << 20) | ((uint32_t)bin << 8); }
  }
}

// ---- fused: L2 histogram of in-bin elements + direct key emission for
//      definite-top (top12 > pref, provably < 6000 of them) + global stash of
//      in-bin element INDICES (~N/16 per batch, cap 32768 = 2x margin).
//      Kills the third full read pass. ----
__global__ __launch_bounds__(256) void k_hist2c(const float* __restrict__ probs, char* ws){
  __shared__ uint32_t h[4096];
  uint32_t* state = (uint32_t*)ws;
  int b = blockIdx.y, t = threadIdx.x;
  uint32_t pref = state[b];
  for (int k = t; k < 4096; k += 256) h[k] = 0;
  __syncthreads();
  const float2* p2 = (const float2*)probs + (size_t)b * NN;
  uint64_t* keys  = (uint64_t*)(ws + OFF_KEY)   + (size_t)b * CAND_CAP;
  uint32_t* stash = (uint32_t*)(ws + OFF_STASH) + (size_t)b * STASH_CAP;
  int base = blockIdx.x * 2048;
  for (int k = 0; k < 8; ++k){
    int i = base + k*256 + t;
    bool ok = i < NN;
    uint32_t u = ok ? fkey(p2[i].y) : 0u;
    uint32_t top12 = u >> 20;
    bool isTop  = ok && top12 >  pref;
    bool isPref = ok && top12 == pref;
    if (isPref) atomicAdd(&h[(u >> 8) & 0xFFFu], 1u);
    uint32_t s1 = wave_reserve(isTop, &state[CNT_KEY(b)]);
    if (isTop && s1 < CAND_CAP)
      keys[s1] = ((uint64_t)u << 32) | (uint32_t)(~(uint32_t)i);
    uint32_t s2 = wave_reserve(isPref, &state[CNT_STASH(b)]);
    if (isPref && s2 < STASH_CAP)
      stash[s2] = (uint32_t)i;
  }
  __syncthreads();
  uint32_t* gh = (uint32_t*)(ws + OFF_HIST2) + b*4096;
  for (int k = t; k < 4096; k += 256) if (h[k]) atomicAdd(&gh[k], h[k]);
}

// ---- filter stashed in-bin elements by the final 20-bit threshold ----
__global__ __launch_bounds__(256) void k_compact2(const float* __restrict__ probs, char* ws){
  uint32_t* state = (uint32_t*)ws;
  int b = blockIdx.y, t = threadIdx.x;
  uint32_t thr = state[16 + b];
  uint32_t nS = state[CNT_STASH(b)]; if (nS > STASH_CAP) nS = STASH_CAP;
  const float2* p2 = (const float2*)probs + (size_t)b * NN;
  const uint32_t* stash = (const uint32_t*)(ws + OFF_STASH) + (size_t)b * STASH_CAP;
  uint64_t* keys = (uint64_t*)(ws + OFF_KEY) + (size_t)b * CAND_CAP;
  for (uint32_t e0 = blockIdx.x*256; e0 < nS; e0 += 8*256){
    uint32_t e = e0 + t;
    bool hit = false; uint32_t u = 0, idx = 0;
    if (e < nS){
      idx = stash[e];
      u = fkey(p2[idx].y);
      hit = (u >= thr);
    }
    uint32_t pos = wave_reserve(hit, &state[CNT_KEY(b)]);
    if (hit && pos < CAND_CAP)
      keys[pos] = ((uint64_t)u << 32) | (uint32_t)(~idx);
  }
}

// ---- rank-sort: rank = #{keys > mine}; scatter id to sorted[rank] if rank < 6000 ----
__global__ __launch_bounds__(256) void k_rank(char* ws){
  __shared__ uint64_t tile[1024];
  uint32_t* state = (uint32_t*)ws;
  int b = blockIdx.y, t = threadIdx.x;
  uint32_t cnt = state[CNT_KEY(b)]; if (cnt > CAND_CAP) cnt = CAND_CAP;
  const uint64_t* kb = (const uint64_t*)(ws + OFF_KEY) + (size_t)b * CAND_CAP;
  uint32_t* sorted = (uint32_t*)(ws + OFF_SORTED);
  int kidx = blockIdx.x*256 + t;
  uint64_t my = (kidx < (int)cnt) ? kb[kidx] : 0ull;
  uint32_t r0 = 0, r1 = 0, r2 = 0, r3 = 0;
  for (int base = 0; base < CAND_CAP; base += 1024){
    for (int e = t; e < 1024; e += 256){
      int g = base + e;
      tile[e] = (g < (int)cnt) ? kb[g] : 0ull;
    }
    __syncthreads();
    int lim = (int)cnt - base; if (lim < 0) lim = 0; if (lim > 1024) lim = 1024;
    int lim4 = lim & ~3;
    for (int e = 0; e < lim4; e += 4){
      r0 += (tile[e]   > my) ? 1u : 0u;
      r1 += (tile[e+1] > my) ? 1u : 0u;
      r2 += (tile[e+2] > my) ? 1u : 0u;
      r3 += (tile[e+3] > my) ? 1u : 0u;
    }
    for (int e = lim4; e < lim; ++e) r0 += (tile[e] > my) ? 1u : 0u;
    __syncthreads();
  }
  uint32_t rank = r0 + r1 + r2 + r3;
  if (kidx < (int)cnt && rank < PRE_NMS){
    uint32_t id = ~(uint32_t)(my & 0xFFFFFFFFull);
    sorted[b*PRE_NMS + rank] = id;
  }
}

// ---- gather deltas/anchors at sorted ids, regress, clip, precompute areas ----
__global__ void k_gather(const float* __restrict__ boff, const float* __restrict__ anc, char* ws){
#pragma clang fp contract(off)
  int t = blockIdx.x*256 + threadIdx.x;
  if (t >= BATCH*PRE_NMS) return;
  int b = t / PRE_NMS, k = t - b*PRE_NMS;
  const uint32_t* sorted = (const uint32_t*)(ws + OFF_SORTED);
  float4* boxes = (float4*)(ws + OFF_BOXES);
  float* areas = (float*)(ws + OFF_AREAS);
  uint32_t id = sorted[b*PRE_NMS + k];
  float4 d4 = ((const float4*)boff)[(size_t)b*NN + id];
  float4 a4 = ((const float4*)anc )[(size_t)b*NN + id];
  float d0 = d4.x*0.1f, d1 = d4.y*0.1f, d2 = d4.z*0.2f, d3 = d4.w*0.2f;
  float h = a4.z - a4.x;
  float w = a4.w - a4.y;
  float cy = a4.x + 0.5f*h + d0*h;
  float cx = a4.y + 0.5f*w + d1*w;
  float h2 = h * expf(d2);
  float w2 = w * expf(d3);
  float y1 = cy - 0.5f*h2, x1 = cx - 0.5f*w2;
  float y2 = cy + 0.5f*h2, x2 = cx + 0.5f*w2;
  y1 = fminf(fmaxf(y1, 0.f), 1.f);
  x1 = fminf(fmaxf(x1, 0.f), 1.f);
  y2 = fminf(fmaxf(y2, 0.f), 1.f);
  x2 = fminf(fmaxf(x2, 0.f), 1.f);
  boxes[(size_t)b*NPAD + k] = make_float4(y1, x1, y2, x2);
  areas[(size_t)b*NPAD + k] = (y2 - y1) * (x2 - x1);
}

// ---- sparse edge build: all pairs i<j with IoU > 0.7 (tiled 64x64, upper triangle) ----
// Exact division-free test (bit-identical decisions, see R5 notes):
//   RN32(inter/uni) > 0.7f  <=>  (double)inter >= M*(double)uni, M=0x1.666667p-1.
// Index-validity hoisted into a precomputed 64-bit validmask per lane
// (covers j>i, j<PRE_NMS, and poison in pad rows/cols).
__global__ __launch_bounds__(64) void k_edges(char* ws){
#pragma clang fp contract(off)
  const double M = 0x1.666667p-1;        // 0.7000000178813934326171875
  uint32_t* state = (uint32_t*)ws;
  const float4* boxes = (const float4*)(ws + OFF_BOXES);
  const float* areas = (const float*)(ws + OFF_AREAS);
  uint32_t* edges = (uint32_t*)(ws + OFF_EDGES);
  int b = blockIdx.y, t = threadIdx.x;
  int p = blockIdx.x, ti = 0;
  while (p >= NTILE - ti){ p -= NTILE - ti; ++ti; }   // triangular decode
  int tj = ti + p;
  __shared__ float4 cb[64];
  __shared__ float  ca[64];
  int j0 = tj*64 + t;
  cb[t] = boxes[(size_t)b*NPAD + j0];
  ca[t] = areas[(size_t)b*NPAD + j0];
  __syncthreads();
  int i = ti*64 + t;
  float4 bi = boxes[(size_t)b*NPAD + i];   // pad rows garbage -> masked below
  float ai = areas[(size_t)b*NPAD + i];
  // validmask: bit jj set iff (tj*64+jj > i) && (tj*64+jj < PRE_NMS)
  int rem = PRE_NMS - tj*64;
  uint64_t m2 = (rem >= 64) ? ~0ull : ((rem <= 0) ? 0ull : ((1ull << rem) - 1ull));
  uint64_t m1 = (tj > ti) ? ~0ull : ((t == 63) ? 0ull : (~0ull << (t + 1)));
  uint64_t vm = m1 & m2;
  uint64_t hitmask = 0;
#pragma unroll 8
  for (int jj = 0; jj < 64; ++jj){
    float4 bj = cb[jj];
    float yy1 = fmaxf(bi.x, bj.x);
    float xx1 = fmaxf(bi.y, bj.y);
    float yy2 = fminf(bi.z, bj.z);
    float xx2 = fminf(bi.w, bj.w);
    float ih = fmaxf(yy2 - yy1, 0.f);
    float iw = fmaxf(xx2 - xx1, 0.f);
    float inter = ih * iw;
    float uni = ai + ca[jj] - inter + 1e-9f;
    bool hit = (double)inter >= M * (double)uni;
    hitmask |= hit ? (1ull << jj) : 0ull;
  }
  hitmask &= vm;
  // drain: hits are rare, loop runs ~0-1 times per wave.
  while (__any((int)(hitmask != 0ull))){
    bool pred = hitmask != 0ull;
    int jj = pred ? (__ffsll((unsigned long long)hitmask) - 1) : 0;
    uint32_t slot = wave_reserve(pred, &state[CNT_EDGE(b)]);
    if (pred && slot < EDGE_CAP)
      edges[(size_t)b*EDGE_CAP + slot] = (uint32_t)i | ((uint32_t)(tj*64 + jj) << 13);
    hitmask &= hitmask - 1;
  }
}

// ---- greedy NMS sweep (windowed, sparse-edge driven) ----
__global__ __launch_bounds__(256) void k_scan(char* ws, float* __restrict__ out){
  __shared__ uint32_t deg[NPAD + 1];
  __shared__ uint32_t offs[NPAD + 1];
  __shared__ uint32_t ebuf[EDGE_CAP];      // (i&63)<<16 | j
  __shared__ uint32_t suppr[NW32];
  __shared__ uint32_t part[256];
  __shared__ uint32_t adjlo[64];
  __shared__ uint32_t adjhi[64];
  uint32_t* state = (uint32_t*)ws;
  const uint32_t* eb = (const uint32_t*)(ws + OFF_EDGES) + (size_t)blockIdx.x * EDGE_CAP;
  const float4* boxes = (const float4*)(ws + OFF_BOXES);
  int b = blockIdx.x, t = threadIdx.x;

  for (int i = t; i <= NPAD; i += 256) deg[i] = 0;
  for (int i = t; i < NW32; i += 256) suppr[i] = 0;
  __syncthreads();
  uint32_t E = state[CNT_EDGE(b)]; if (E > EDGE_CAP) E = EDGE_CAP;
  for (uint32_t e = t; e < E; e += 256) atomicAdd(&deg[eb[e] & 0x1FFFu], 1u);
  __syncthreads();
  const int CH = 24;
  uint32_t s = 0;
  for (int k = 0; k < CH; ++k){ int i = t*CH + k; if (i <= NPAD) s += deg[i]; }
  part[t] = s;
  __syncthreads();
  if (t == 0){ uint32_t run = 0; for (int c = 0; c < 256; ++c){ uint32_t v = part[c]; part[c] = run; run += v; } }
  __syncthreads();
  uint32_t run = part[t];
  for (int k = 0; k < CH; ++k){ int i = t*CH + k; if (i <= NPAD){ offs[i] = run; run += deg[i]; } }
  __syncthreads();
  for (int i = t; i <= NPAD; i += 256) deg[i] = 0;
  __syncthreads();
  for (uint32_t e = t; e < E; e += 256){
    uint32_t ed = eb[e];
    uint32_t ii = ed & 0x1FFFu, jj = ed >> 13;
    uint32_t slot = atomicAdd(&deg[ii], 1u);
    ebuf[offs[ii] + slot] = ((ii & 63u) << 16) | jj;
  }
  __syncthreads();
  if (t >= 64) return;
  int lane = t;
  uint32_t nsel = 0;
  for (int w = 0; w < NTILE && nsel < NUM_PROP; ++w){
    int base = w*64;
    adjlo[lane] = 0; adjhi[lane] = 0;
    float4 mybox = boxes[(size_t)b*NPAD + base + lane];
    uint64_t sup = (uint64_t)suppr[2*w] | ((uint64_t)suppr[2*w + 1] << 32);
    uint64_t live = ~sup;
    int valid = PRE_NMS - base;
    if (valid < 64) live &= ((1ull << valid) - 1ull);
    uint32_t r0 = offs[base], r1 = offs[base + 64];
    bool anyIn = false;
    for (uint32_t idx = r0 + (uint32_t)lane; idx < r1; idx += 64){
      uint32_t e = ebuf[idx];
      uint32_t il = e >> 16, j = e & 0xFFFFu;
      if (((live >> il) & 1ull) && j < (uint32_t)(base + 64)){
        uint32_t l2 = j - (uint32_t)base;
        if (l2 < 32) atomicOr(&adjlo[il], 1u << l2);
        else         atomicOr(&adjhi[il], 1u << (l2 - 32));
        anyIn = true;
      }
    }
    anyIn = __any((int)anyIn);
    uint64_t sel;
    if (!anyIn){
      uint32_t cnt = __popcll(live);
      uint32_t remn = NUM_PROP - nsel;
      uint32_t take = cnt < remn ? cnt : remn;
      if (live & (1ull << lane)){
        uint32_t r = __popcll(live & ((1ull << lane) - 1ull));
        if (r < take) ((float4*)out)[(size_t)b*NUM_PROP + nsel + r] = mybox;
      }
      nsel += take;
      sel = live;
    } else {
      uint64_t row = (uint64_t)adjlo[lane] | ((uint64_t)adjhi[lane] << 32);
      uint64_t m = live;
      sel = 0;
      while (m && nsel < NUM_PROP){
        int f = __ffsll((unsigned long long)m) - 1;
        m &= m - 1;
        sel |= 1ull << f;
        if (lane == f) ((float4*)out)[(size_t)b*NUM_PROP + nsel] = mybox;
        nsel++;
        m &= ~shfl64(row, f);
      }
    }
    if (nsel >= NUM_PROP) break;
    for (uint32_t idx = r0 + (uint32_t)lane; idx < r1; idx += 64){
      uint32_t e = ebuf[idx];
      uint32_t il = e >> 16, j = e & 0xFFFFu;
      if (((sel >> il) & 1ull) && j >= (uint32_t)(base + 64))
        atomicOr(&suppr[j >> 5], 1u << (j & 31));
    }
  }
  for (uint32_t r = nsel + (uint32_t)lane; r < NUM_PROP; r += 64)
    ((float4*)out)[(size_t)b*NUM_PROP + r] = make_float4(0.f, 0.f, 0.f, 0.f);
}

extern "C" void kernel_launch(void* const* d_in, const int* in_sizes, int n_in,
                              void* d_out, int out_size, void* d_ws, size_t ws_size,
                              hipStream_t stream){
  const float* probs = (const float*)d_in[0];
  const float* boff  = (const float*)d_in[1];
  const float* anc   = (const float*)d_in[2];
  char* ws = (char*)d_ws;
  float* out = (float*)d_out;

  hipMemsetAsync(ws, 0, OFF_KEY, stream);  // zero state + both histograms
  k_hist1   <<<dim3(128, BATCH), 256, 0, stream>>>(probs, ws);
  k_resolve <<<BATCH, 256, 0, stream>>>(ws, 1);
  k_hist2c  <<<dim3(128, BATCH), 256, 0, stream>>>(probs, ws);
  k_resolve <<<BATCH, 256, 0, stream>>>(ws, 2);
  k_compact2<<<dim3(8, BATCH), 256, 0, stream>>>(probs, ws);
  k_rank    <<<dim3(CAND_CAP/256, BATCH), 256, 0, stream>>>(ws);
  k_gather  <<<(BATCH*PRE_NMS + 255)/256, 256, 0, stream>>>(boff, anc, ws);
  k_edges   <<<dim3(NTILE*(NTILE+1)/2, BATCH), 64, 0, stream>>>(ws);
  k_scan    <<<BATCH, 256, 0, stream>>>(ws, out);
}

// Round 8
// 264.913 us; speedup vs baseline: 1.1504x; 1.1504x over previous
//
#include <hip/hip_runtime.h>
#include <stdint.h>

// ProposalLayer: top-6000 select -> bbox regression+clip -> greedy NMS -> 2000 proposals
// B=8, N=261888, all float32.

#define BATCH   8
#define NN      261888
#define PRE_NMS 6000
#define NUM_PROP 2000
#define CAND_CAP 8192
#define EDGE_CAP 16384
#define NTILE   94         // ceil(6000/64)
#define NPAD    6016       // NTILE*64
#define NW32    188

// workspace layout (bytes)
#define OFF_HIST1  4096
#define OFF_HIST2  (OFF_HIST1 + BATCH*4096*4)
#define OFF_KEY    (OFF_HIST2 + BATCH*4096*4)          // memset covers [0, OFF_KEY)
#define OFF_SORTED (OFF_KEY + BATCH*CAND_CAP*8)
#define OFF_BOXES  (OFF_SORTED + BATCH*PRE_NMS*4)
#define OFF_EDGES  (OFF_BOXES + BATCH*NPAD*16)
#define WS_NEED    (OFF_EDGES + BATCH*EDGE_CAP*4)      // ~2.28 MB
// Aliased (written only after their hosts are dead):
//  sboxes (spatial order, 8*6016*16 = 770048 B) over HIST1+HIST2+KEY (786432 B),
//    written by k_cellsort AFTER k_resolve/k_rank have consumed those regions.
#define OFF_SBOX   OFF_HIST1
//  sorig (u16, 8*6016*2 = 96256 B) + tile meta (8*94*6*4 = 18048 B) over SORTED
//    (192000 B), written AFTER k_gather consumed sorted[].
#define OFF_SORIG  OFF_SORTED
#define OFF_TMETA  (OFF_SORTED + 98304)

// state u32 indices: [b]=L1 bin, [8+b]=Krem, [16+b]=threshold.
// Counters spread 128B (32 u32) apart: one cache line per batch.
#define CNT_KEY(b)   (64  + (b)*32)
#define CNT_EDGE(b)  (320 + (b)*32)

__device__ __forceinline__ uint32_t fkey(float s){
  uint32_t b = __float_as_uint(s);
  return (b & 0x80000000u) ? ~b : (b | 0x80000000u);   // order-preserving float->u32
}

__device__ __forceinline__ uint64_t shfl64(uint64_t v, int src){
  uint32_t lo = __shfl((uint32_t)(v & 0xFFFFFFFFull), src, 64);
  uint32_t hi = __shfl((uint32_t)(v >> 32), src, 64);
  return (uint64_t)lo | ((uint64_t)hi << 32);
}

// wave-aggregated counter reservation: one atomic per wave instead of per lane.
__device__ __forceinline__ uint32_t wave_reserve(bool pred, uint32_t* ctr){
  uint64_t m = __ballot((int)pred);
  if (!m) return 0xFFFFFFFFu;
  int lane = (int)(threadIdx.x & 63u);
  int leader = __ffsll((unsigned long long)m) - 1;
  uint32_t base = 0;
  if (lane == leader) base = atomicAdd(ctr, (uint32_t)__popcll(m));
  base = __shfl(base, leader, 64);
  return base + (uint32_t)__popcll(m & ((1ull << lane) - 1ull));
}

// ---- level-1 histogram of top 12 bits of fkey ----
__global__ void k_hist1(const float* __restrict__ probs, char* ws){
  __shared__ uint32_t h[4096];
  int b = blockIdx.y;
  for (int t = threadIdx.x; t < 4096; t += 256) h[t] = 0;
  __syncthreads();
  const float2* p2 = (const float2*)probs + (size_t)b * NN;
  int base = blockIdx.x * 2048;
  for (int k = 0; k < 8; ++k){
    int i = base + k*256 + threadIdx.x;
    if (i < NN) atomicAdd(&h[fkey(p2[i].y) >> 20], 1u);
  }
  __syncthreads();
  uint32_t* gh = (uint32_t*)(ws + OFF_HIST1) + b*4096;
  for (int t = threadIdx.x; t < 4096; t += 256) if (h[t]) atomicAdd(&gh[t], h[t]);
}

// ---- level-2 histogram (bits 19:8) among elements matching L1 prefix ----
__global__ void k_hist2(const float* __restrict__ probs, char* ws){
  __shared__ uint32_t h[4096];
  uint32_t* state = (uint32_t*)ws;
  int b = blockIdx.y;
  uint32_t pref = state[b];
  for (int t = threadIdx.x; t < 4096; t += 256) h[t] = 0;
  __syncthreads();
  const float2* p2 = (const float2*)probs + (size_t)b * NN;
  int base = blockIdx.x * 2048;
  for (int k = 0; k < 8; ++k){
    int i = base + k*256 + threadIdx.x;
    if (i < NN){
      uint32_t u = fkey(p2[i].y);
      if ((u >> 20) == pref) atomicAdd(&h[(u >> 8) & 0xFFFu], 1u);
    }
  }
  __syncthreads();
  uint32_t* gh = (uint32_t*)(ws + OFF_HIST2) + b*4096;
  for (int t = threadIdx.x; t < 4096; t += 256) if (h[t]) atomicAdd(&gh[t], h[t]);
}

// ---- find histogram bin where cumulative-from-top crosses K ----
__global__ void k_resolve(char* ws, int level){
  uint32_t* state = (uint32_t*)ws;
  const uint32_t* gh = (const uint32_t*)(ws + (level == 1 ? OFF_HIST1 : OFF_HIST2)) + blockIdx.x*4096;
  __shared__ uint32_t part[256];
  int b = blockIdx.x, t = threadIdx.x;
  uint32_t s = 0;
  for (int k = 0; k < 16; ++k) s += gh[t*16 + k];
  part[t] = s;
  __syncthreads();
  if (t == 0){
    uint32_t K = (level == 1) ? (uint32_t)PRE_NMS : state[8 + b];
    uint32_t cum = 0; int c = 255;
    for (; c > 0; --c){ if (cum + part[c] >= K) break; cum += part[c]; }
    uint32_t rem = K - cum;
    uint32_t cum2 = 0; int bin = c*16;
    for (int k = 15; k >= 0; --k){
      uint32_t v = gh[c*16 + k];
      if (cum2 + v >= rem){ bin = c*16 + k; rem = rem - cum2; break; }
      cum2 += v;
    }
    if (level == 1){ state[b] = (uint32_t)bin; state[8 + b] = rem; }
    else           { state[16 + b] = (state[b] << 20) | ((uint32_t)bin << 8); }
  }
}

// ---- compact all elements with fkey >= threshold into distinct u64 keys ----
__global__ void k_compact(const float* __restrict__ probs, char* ws){
  uint32_t* state = (uint32_t*)ws;
  uint64_t* keys = (uint64_t*)(ws + OFF_KEY);
  int b = blockIdx.y;
  uint32_t thr = state[16 + b];
  const float2* p2 = (const float2*)probs + (size_t)b * NN;
  int base = blockIdx.x * 2048;
  for (int k = 0; k < 8; ++k){
    int i = base + k*256 + threadIdx.x;
    bool hit = false; uint32_t u = 0;
    if (i < NN){
      u = fkey(p2[i].y);
      hit = (u >= thr);
    }
    uint32_t pos = wave_reserve(hit, &state[CNT_KEY(b)]);
    if (hit && pos < CAND_CAP)
      keys[(size_t)b*CAND_CAP + pos] = ((uint64_t)u << 32) | (uint32_t)(~(uint32_t)i);
  }
}

// ---- rank-sort: rank = #{keys > mine}; scatter id to sorted[rank] if rank < 6000 ----
__global__ __launch_bounds__(256) void k_rank(char* ws){
  __shared__ uint64_t tile[1024];
  uint32_t* state = (uint32_t*)ws;
  int b = blockIdx.y, t = threadIdx.x;
  uint32_t cnt = state[CNT_KEY(b)]; if (cnt > CAND_CAP) cnt = CAND_CAP;
  const uint64_t* kb = (const uint64_t*)(ws + OFF_KEY) + (size_t)b * CAND_CAP;
  uint32_t* sorted = (uint32_t*)(ws + OFF_SORTED);
  int kidx = blockIdx.x*256 + t;
  uint64_t my = (kidx < (int)cnt) ? kb[kidx] : 0ull;
  uint32_t r0 = 0, r1 = 0, r2 = 0, r3 = 0;
  for (int base = 0; base < CAND_CAP; base += 1024){
    for (int e = t; e < 1024; e += 256){
      int g = base + e;
      tile[e] = (g < (int)cnt) ? kb[g] : 0ull;
    }
    __syncthreads();
    int lim = (int)cnt - base; if (lim < 0) lim = 0; if (lim > 1024) lim = 1024;
    int lim4 = lim & ~3;
    for (int e = 0; e < lim4; e += 4){
      r0 += (tile[e]   > my) ? 1u : 0u;
      r1 += (tile[e+1] > my) ? 1u : 0u;
      r2 += (tile[e+2] > my) ? 1u : 0u;
      r3 += (tile[e+3] > my) ? 1u : 0u;
    }
    for (int e = lim4; e < lim; ++e) r0 += (tile[e] > my) ? 1u : 0u;
    __syncthreads();
  }
  uint32_t rank = r0 + r1 + r2 + r3;
  if (kidx < (int)cnt && rank < PRE_NMS){
    uint32_t id = ~(uint32_t)(my & 0xFFFFFFFFull);
    sorted[b*PRE_NMS + rank] = id;
  }
}

// ---- gather deltas/anchors at sorted ids, regress, clip ----
__global__ void k_gather(const float* __restrict__ boff, const float* __restrict__ anc, char* ws){
#pragma clang fp contract(off)
  int t = blockIdx.x*256 + threadIdx.x;
  if (t >= BATCH*PRE_NMS) return;
  int b = t / PRE_NMS, k = t - b*PRE_NMS;
  const uint32_t* sorted = (const uint32_t*)(ws + OFF_SORTED);
  float4* boxes = (float4*)(ws + OFF_BOXES);
  uint32_t id = sorted[b*PRE_NMS + k];
  float4 d4 = ((const float4*)boff)[(size_t)b*NN + id];
  float4 a4 = ((const float4*)anc )[(size_t)b*NN + id];
  float d0 = d4.x*0.1f, d1 = d4.y*0.1f, d2 = d4.z*0.2f, d3 = d4.w*0.2f;
  float h = a4.z - a4.x;
  float w = a4.w - a4.y;
  float cy = a4.x + 0.5f*h + d0*h;
  float cx = a4.y + 0.5f*w + d1*w;
  float h2 = h * expf(d2);
  float w2 = w * expf(d3);
  float y1 = cy - 0.5f*h2, x1 = cx - 0.5f*w2;
  float y2 = cy + 0.5f*h2, x2 = cx + 0.5f*w2;
  y1 = fminf(fmaxf(y1, 0.f), 1.f);
  x1 = fminf(fmaxf(x1, 0.f), 1.f);
  y2 = fminf(fmaxf(y2, 0.f), 1.f);
  x2 = fminf(fmaxf(x2, 0.f), 1.f);
  boxes[(size_t)b*NPAD + k] = make_float4(y1, x1, y2, x2);
}

// ---- spatial counting sort into 32x8 cells + per-64-box-tile bounds ----
// Any permutation is correct (edges are mapped back to original indices);
// spatial grouping only serves tile-level pruning in k_edges.
__global__ __launch_bounds__(1024) void k_cellsort(char* ws){
  __shared__ uint32_t hist[256];
  __shared__ uint32_t cur[256];
  __shared__ uint16_t cell[PRE_NMS];
  int b = blockIdx.x, t = threadIdx.x;
  const float4* boxes = (const float4*)(ws + OFF_BOXES) + (size_t)b*NPAD;
  float4* sbox = (float4*)(ws + OFF_SBOX) + (size_t)b*NPAD;
  uint16_t* sorig = (uint16_t*)(ws + OFF_SORIG) + (size_t)b*NPAD;
  float* tmeta = (float*)(ws + OFF_TMETA) + (size_t)b*NTILE*6;
  if (t < 256) hist[t] = 0;
  __syncthreads();
  for (int k = t; k < PRE_NMS; k += 1024){
    float4 bx = boxes[k];
    float cy = 0.5f*(bx.x + bx.z), cx = 0.5f*(bx.y + bx.w);
    int iy = (int)(cy*32.f); iy = iy < 0 ? 0 : (iy > 31 ? 31 : iy);
    int ix = (int)(cx*8.f);  ix = ix < 0 ? 0 : (ix > 7 ? 7 : ix);
    int c = (iy << 3) | ix;
    cell[k] = (uint16_t)c;
    atomicAdd(&hist[c], 1u);
  }
  __syncthreads();
  // exclusive prefix over 256 bins (Hillis-Steele)
  if (t < 256) cur[t] = hist[t];
  __syncthreads();
  for (int d = 1; d < 256; d <<= 1){
    uint32_t v = 0;
    if (t < 256 && t >= d) v = cur[t - d];
    __syncthreads();
    if (t < 256) cur[t] += v;
    __syncthreads();
  }
  if (t < 256) cur[t] -= hist[t];
  __syncthreads();
  for (int k = t; k < PRE_NMS; k += 1024){
    uint32_t slot = atomicAdd(&cur[cell[k]], 1u);
    sbox[slot] = boxes[k];
    sorig[slot] = (uint16_t)k;
  }
  for (int k = PRE_NMS + t; k < NPAD; k += 1024){
    sbox[k] = make_float4(3.f, 3.f, 3.f, 3.f);   // far box, h=w=0 -> never hits
    sorig[k] = 0;
  }
  __syncthreads();
  int wid = t >> 6, lane = t & 63;
  for (int tt = wid; tt < NTILE; tt += 16){
    float4 bx = sbox[tt*64 + lane];
    float cy = 0.5f*(bx.x + bx.z), cx = 0.5f*(bx.y + bx.w);
    float h = bx.z - bx.x, w = bx.w - bx.y;
    float cymin = cy, cymax = cy, cxmin = cx, cxmax = cx, hmax = h, wmax = w;
    for (int d = 32; d >= 1; d >>= 1){
      cymin = fminf(cymin, __shfl_xor(cymin, d));
      cymax = fmaxf(cymax, __shfl_xor(cymax, d));
      cxmin = fminf(cxmin, __shfl_xor(cxmin, d));
      cxmax = fmaxf(cxmax, __shfl_xor(cxmax, d));
      hmax  = fmaxf(hmax,  __shfl_xor(hmax,  d));
      wmax  = fmaxf(wmax,  __shfl_xor(wmax,  d));
    }
    if (lane == 0){
      tmeta[tt*6+0] = cymin; tmeta[tt*6+1] = cymax;
      tmeta[tt*6+2] = cxmin; tmeta[tt*6+3] = cxmax;
      tmeta[tt*6+4] = hmax;  tmeta[tt*6+5] = wmax;
    }
  }
}

// ---- sparse edge build on spatially-ordered tiles with conservative pruning ----
// Necessary conditions (real arithmetic on f32 inputs, proof in journal):
//   IoU > 0.7 => ih > 0.7*max(hi,hj) => |dcy| < 0.3*min(hi,hj), symmetric in x.
// Tile pair skipped iff interval gap >= 0.3015*min(tile hmax) + 2e-5 (slack >>
// accumulated f32 error ~1e-6) -> prune is strictly conservative. Surviving
// pairs run the exact division-free M-test (bit-identical to f32 division,
// established R5/R6). Edges mapped to ORIGINAL indices -> edge set unchanged.
__global__ __launch_bounds__(64) void k_edges(char* ws){
#pragma clang fp contract(off)
  const double M = 0x1.666667p-1;        // 0.7000000178813934326171875
  uint32_t* state = (uint32_t*)ws;
  const float4* sbox = (const float4*)(ws + OFF_SBOX);
  const uint16_t* sorig = (const uint16_t*)(ws + OFF_SORIG);
  const float* tmeta = (const float*)(ws + OFF_TMETA);
  uint32_t* edges = (uint32_t*)(ws + OFF_EDGES);
  int b = blockIdx.y, t = threadIdx.x;
  int p = blockIdx.x, ti = 0;
  while (p >= NTILE - ti){ p -= NTILE - ti; ++ti; }   // triangular decode (incl. diagonal)
  int tj = ti + p;
  const float* mi = tmeta + ((size_t)b*NTILE + ti)*6;
  const float* mj = tmeta + ((size_t)b*NTILE + tj)*6;
  float gapy = fmaxf(fmaxf(mj[0] - mi[1], mi[0] - mj[1]), 0.f);
  float gapx = fmaxf(fmaxf(mj[2] - mi[3], mi[2] - mj[3]), 0.f);
  float by = 0.3015f*fminf(mi[4], mj[4]) + 2e-5f;
  float bx = 0.3015f*fminf(mi[5], mj[5]) + 2e-5f;
  if (gapy >= by || gapx >= bx) return;               // uniform across block
  __shared__ float4 cb[64];
  __shared__ float  ca[64];
  __shared__ uint16_t co[64];
  int j0 = tj*64 + t;
  float4 bj0 = sbox[(size_t)b*NPAD + j0];
  cb[t] = bj0;
  ca[t] = (bj0.z - bj0.x)*(bj0.w - bj0.y);
  co[t] = sorig[(size_t)b*NPAD + j0];
  __syncthreads();
  int si = ti*64 + t;
  float4 bi = sbox[(size_t)b*NPAD + si];
  float ai = (bi.z - bi.x)*(bi.w - bi.y);
  uint32_t oi = sorig[(size_t)b*NPAD + si];
  // spatial triangle: all of tile j when tj>ti, else strictly-upper within tile.
  // Pads (h=w=0 boxes at {3,3,3,3}) can never satisfy the hit test.
  uint64_t vm = (ti < tj) ? ~0ull : ((t == 63) ? 0ull : (~0ull << (t + 1)));
  uint64_t hitmask = 0;
#pragma unroll 8
  for (int jj = 0; jj < 64; ++jj){
    float4 bj = cb[jj];
    float yy1 = fmaxf(bi.x, bj.x);
    float xx1 = fmaxf(bi.y, bj.y);
    float yy2 = fminf(bi.z, bj.z);
    float xx2 = fminf(bi.w, bj.w);
    float ih = fmaxf(yy2 - yy1, 0.f);
    float iw = fmaxf(xx2 - xx1, 0.f);
    float inter = ih * iw;
    float uni = ai + ca[jj] - inter + 1e-9f;
    bool hit = (double)inter >= M * (double)uni;
    hitmask |= hit ? (1ull << jj) : 0ull;
  }
  hitmask &= vm;
  while (__any((int)(hitmask != 0ull))){
    bool pred = hitmask != 0ull;
    int jj = pred ? (__ffsll((unsigned long long)hitmask) - 1) : 0;
    uint32_t slot = wave_reserve(pred, &state[CNT_EDGE(b)]);
    if (pred && slot < EDGE_CAP){
      uint32_t oj = co[jj];
      uint32_t lo = oi < oj ? oi : oj;
      uint32_t hi = oi < oj ? oj : oi;
      edges[(size_t)b*EDGE_CAP + slot] = lo | (hi << 13);
    }
    hitmask &= hitmask - 1;
  }
}

// ---- greedy NMS sweep (windowed, sparse-edge driven) ----
__global__ __launch_bounds__(256) void k_scan(char* ws, float* __restrict__ out){
  __shared__ uint32_t deg[NPAD + 1];
  __shared__ uint32_t offs[NPAD + 1];
  __shared__ uint32_t ebuf[EDGE_CAP];      // (i&63)<<16 | j
  __shared__ uint32_t suppr[NW32];
  __shared__ uint32_t part[256];
  __shared__ uint32_t adjlo[64];
  __shared__ uint32_t adjhi[64];
  uint32_t* state = (uint32_t*)ws;
  const uint32_t* eb = (const uint32_t*)(ws + OFF_EDGES) + (size_t)blockIdx.x * EDGE_CAP;
  const float4* boxes = (const float4*)(ws + OFF_BOXES);
  int b = blockIdx.x, t = threadIdx.x;

  for (int i = t; i <= NPAD; i += 256) deg[i] = 0;
  for (int i = t; i < NW32; i += 256) suppr[i] = 0;
  __syncthreads();
  uint32_t E = state[CNT_EDGE(b)]; if (E > EDGE_CAP) E = EDGE_CAP;
  for (uint32_t e = t; e < E; e += 256) atomicAdd(&deg[eb[e] & 0x1FFFu], 1u);
  __syncthreads();
  const int CH = 24;
  uint32_t s = 0;
  for (int k = 0; k < CH; ++k){ int i = t*CH + k; if (i <= NPAD) s += deg[i]; }
  part[t] = s;
  __syncthreads();
  if (t == 0){ uint32_t run = 0; for (int c = 0; c < 256; ++c){ uint32_t v = part[c]; part[c] = run; run += v; } }
  __syncthreads();
  uint32_t run = part[t];
  for (int k = 0; k < CH; ++k){ int i = t*CH + k; if (i <= NPAD){ offs[i] = run; run += deg[i]; } }
  __syncthreads();
  for (int i = t; i <= NPAD; i += 256) deg[i] = 0;
  __syncthreads();
  for (uint32_t e = t; e < E; e += 256){
    uint32_t ed = eb[e];
    uint32_t ii = ed & 0x1FFFu, jj = ed >> 13;
    uint32_t slot = atomicAdd(&deg[ii], 1u);
    ebuf[offs[ii] + slot] = ((ii & 63u) << 16) | jj;
  }
  __syncthreads();
  if (t >= 64) return;
  int lane = t;
  uint32_t nsel = 0;
  for (int w = 0; w < NTILE && nsel < NUM_PROP; ++w){
    int base = w*64;
    adjlo[lane] = 0; adjhi[lane] = 0;
    float4 mybox = boxes[(size_t)b*NPAD + base + lane];
    uint64_t sup = (uint64_t)suppr[2*w] | ((uint64_t)suppr[2*w + 1] << 32);
    uint64_t live = ~sup;
    int valid = PRE_NMS - base;
    if (valid < 64) live &= ((1ull << valid) - 1ull);
    uint32_t r0 = offs[base], r1 = offs[base + 64];
    bool anyIn = false;
    for (uint32_t idx = r0 + (uint32_t)lane; idx < r1; idx += 64){
      uint32_t e = ebuf[idx];
      uint32_t il = e >> 16, j = e & 0xFFFFu;
      if (((live >> il) & 1ull) && j < (uint32_t)(base + 64)){
        uint32_t l2 = j - (uint32_t)base;
        if (l2 < 32) atomicOr(&adjlo[il], 1u << l2);
        else         atomicOr(&adjhi[il], 1u << (l2 - 32));
        anyIn = true;
      }
    }
    anyIn = __any((int)anyIn);
    uint64_t sel;
    if (!anyIn){
      uint32_t cnt = __popcll(live);
      uint32_t remn = NUM_PROP - nsel;
      uint32_t take = cnt < remn ? cnt : remn;
      if (live & (1ull << lane)){
        uint32_t r = __popcll(live & ((1ull << lane) - 1ull));
        if (r < take) ((float4*)out)[(size_t)b*NUM_PROP + nsel + r] = mybox;
      }
      nsel += take;
      sel = live;
    } else {
      uint64_t row = (uint64_t)adjlo[lane] | ((uint64_t)adjhi[lane] << 32);
      uint64_t m = live;
      sel = 0;
      while (m && nsel < NUM_PROP){
        int f = __ffsll((unsigned long long)m) - 1;
        m &= m - 1;
        sel |= 1ull << f;
        if (lane == f) ((float4*)out)[(size_t)b*NUM_PROP + nsel] = mybox;
        nsel++;
        m &= ~shfl64(row, f);
      }
    }
    if (nsel >= NUM_PROP) break;
    for (uint32_t idx = r0 + (uint32_t)lane; idx < r1; idx += 64){
      uint32_t e = ebuf[idx];
      uint32_t il = e >> 16, j = e & 0xFFFFu;
      if (((sel >> il) & 1ull) && j >= (uint32_t)(base + 64))
        atomicOr(&suppr[j >> 5], 1u << (j & 31));
    }
  }
  for (uint32_t r = nsel + (uint32_t)lane; r < NUM_PROP; r += 64)
    ((float4*)out)[(size_t)b*NUM_PROP + r] = make_float4(0.f, 0.f, 0.f, 0.f);
}

extern "C" void kernel_launch(void* const* d_in, const int* in_sizes, int n_in,
                              void* d_out, int out_size, void* d_ws, size_t ws_size,
                              hipStream_t stream){
  const float* probs = (const float*)d_in[0];
  const float* boff  = (const float*)d_in[1];
  const float* anc   = (const float*)d_in[2];
  char* ws = (char*)d_ws;
  float* out = (float*)d_out;

  hipMemsetAsync(ws, 0, OFF_KEY, stream);  // zero state + both histograms
  k_hist1   <<<dim3(128, BATCH), 256, 0, stream>>>(probs, ws);
  k_resolve <<<BATCH, 256, 0, stream>>>(ws, 1);
  k_hist2   <<<dim3(128, BATCH), 256, 0, stream>>>(probs, ws);
  k_resolve <<<BATCH, 256, 0, stream>>>(ws, 2);
  k_compact <<<dim3(128, BATCH), 256, 0, stream>>>(probs, ws);
  k_rank    <<<dim3(CAND_CAP/256, BATCH), 256, 0, stream>>>(ws);
  k_gather  <<<(BATCH*PRE_NMS + 255)/256, 256, 0, stream>>>(boff, anc, ws);
  k_cellsort<<<BATCH, 1024, 0, stream>>>(ws);
  k_edges   <<<dim3(NTILE*(NTILE+1)/2, BATCH), 64, 0, stream>>>(ws);
  k_scan    <<<BATCH, 256, 0, stream>>>(ws, out);
}

// Round 9
// 255.261 us; speedup vs baseline: 1.1939x; 1.0378x over previous
//
#include <hip/hip_runtime.h>
#include <stdint.h>

// ProposalLayer: top-6000 select -> bbox regression+clip -> greedy NMS -> 2000 proposals
// B=8, N=261888, all float32.

#define BATCH   8
#define NN      261888
#define PRE_NMS 6000
#define NUM_PROP 2000
#define CAND_CAP 8192
#define EDGE_CAP 16384
#define NTILE   94         // ceil(6000/64)
#define NPAD    6016       // NTILE*64
#define NW32    188

// workspace layout (bytes)
#define OFF_HIST1  4096
#define OFF_HIST2  (OFF_HIST1 + BATCH*4096*4)
#define OFF_KEY    (OFF_HIST2 + BATCH*4096*4)          // memset covers [0, OFF_KEY)
#define OFF_SORTED (OFF_KEY + BATCH*CAND_CAP*8)
#define OFF_BOXES  (OFF_SORTED + BATCH*PRE_NMS*4)
#define OFF_EDGES  (OFF_BOXES + BATCH*NPAD*16)
#define WS_NEED    (OFF_EDGES + BATCH*EDGE_CAP*4)      // ~2.28 MB
// Aliased (written only after their hosts are dead):
#define OFF_SBOX   OFF_HIST1
#define OFF_SORIG  OFF_SORTED
#define OFF_TMETA  (OFF_SORTED + 98304)

// state u32 indices: [b]=L1 bin, [8+b]=Krem, [16+b]=threshold.
#define CNT_KEY(b)   (64  + (b)*32)
#define CNT_EDGE(b)  (320 + (b)*32)

__device__ __forceinline__ uint32_t fkey(float s){
  uint32_t b = __float_as_uint(s);
  return (b & 0x80000000u) ? ~b : (b | 0x80000000u);   // order-preserving float->u32
}

__device__ __forceinline__ uint64_t shfl64(uint64_t v, int src){
  uint32_t lo = __shfl((uint32_t)(v & 0xFFFFFFFFull), src, 64);
  uint32_t hi = __shfl((uint32_t)(v >> 32), src, 64);
  return (uint64_t)lo | ((uint64_t)hi << 32);
}

// wave-aggregated counter reservation: one atomic per wave instead of per lane.
__device__ __forceinline__ uint32_t wave_reserve(bool pred, uint32_t* ctr){
  uint64_t m = __ballot((int)pred);
  if (!m) return 0xFFFFFFFFu;
  int lane = (int)(threadIdx.x & 63u);
  int leader = __ffsll((unsigned long long)m) - 1;
  uint32_t base = 0;
  if (lane == leader) base = atomicAdd(ctr, (uint32_t)__popcll(m));
  base = __shfl(base, leader, 64);
  return base + (uint32_t)__popcll(m & ((1ull << lane) - 1ull));
}

// ---- level-1 histogram of top 12 bits of fkey ----
__global__ void k_hist1(const float* __restrict__ probs, char* ws){
  __shared__ uint32_t h[4096];
  int b = blockIdx.y;
  for (int t = threadIdx.x; t < 4096; t += 256) h[t] = 0;
  __syncthreads();
  const float2* p2 = (const float2*)probs + (size_t)b * NN;
  int base = blockIdx.x * 2048;
  for (int k = 0; k < 8; ++k){
    int i = base + k*256 + threadIdx.x;
    if (i < NN) atomicAdd(&h[fkey(p2[i].y) >> 20], 1u);
  }
  __syncthreads();
  uint32_t* gh = (uint32_t*)(ws + OFF_HIST1) + b*4096;
  for (int t = threadIdx.x; t < 4096; t += 256) if (h[t]) atomicAdd(&gh[t], h[t]);
}

// ---- level-2 histogram (bits 19:8) among elements matching L1 prefix ----
__global__ void k_hist2(const float* __restrict__ probs, char* ws){
  __shared__ uint32_t h[4096];
  uint32_t* state = (uint32_t*)ws;
  int b = blockIdx.y;
  uint32_t pref = state[b];
  for (int t = threadIdx.x; t < 4096; t += 256) h[t] = 0;
  __syncthreads();
  const float2* p2 = (const float2*)probs + (size_t)b * NN;
  int base = blockIdx.x * 2048;
  for (int k = 0; k < 8; ++k){
    int i = base + k*256 + threadIdx.x;
    if (i < NN){
      uint32_t u = fkey(p2[i].y);
      if ((u >> 20) == pref) atomicAdd(&h[(u >> 8) & 0xFFFu], 1u);
    }
  }
  __syncthreads();
  uint32_t* gh = (uint32_t*)(ws + OFF_HIST2) + b*4096;
  for (int t = threadIdx.x; t < 4096; t += 256) if (h[t]) atomicAdd(&gh[t], h[t]);
}

// ---- find histogram bin where cumulative-from-top crosses K ----
__global__ void k_resolve(char* ws, int level){
  uint32_t* state = (uint32_t*)ws;
  const uint32_t* gh = (const uint32_t*)(ws + (level == 1 ? OFF_HIST1 : OFF_HIST2)) + blockIdx.x*4096;
  __shared__ uint32_t part[256];
  int b = blockIdx.x, t = threadIdx.x;
  uint32_t s = 0;
  for (int k = 0; k < 16; ++k) s += gh[t*16 + k];
  part[t] = s;
  __syncthreads();
  if (t == 0){
    uint32_t K = (level == 1) ? (uint32_t)PRE_NMS : state[8 + b];
    uint32_t cum = 0; int c = 255;
    for (; c > 0; --c){ if (cum + part[c] >= K) break; cum += part[c]; }
    uint32_t rem = K - cum;
    uint32_t cum2 = 0; int bin = c*16;
    for (int k = 15; k >= 0; --k){
      uint32_t v = gh[c*16 + k];
      if (cum2 + v >= rem){ bin = c*16 + k; rem = rem - cum2; break; }
      cum2 += v;
    }
    if (level == 1){ state[b] = (uint32_t)bin; state[8 + b] = rem; }
    else           { state[16 + b] = (state[b] << 20) | ((uint32_t)bin << 8); }
  }
}

// ---- compact all elements with fkey >= threshold into distinct u64 keys ----
__global__ void k_compact(const float* __restrict__ probs, char* ws){
  uint32_t* state = (uint32_t*)ws;
  uint64_t* keys = (uint64_t*)(ws + OFF_KEY);
  int b = blockIdx.y;
  uint32_t thr = state[16 + b];
  const float2* p2 = (const float2*)probs + (size_t)b * NN;
  int base = blockIdx.x * 2048;
  for (int k = 0; k < 8; ++k){
    int i = base + k*256 + threadIdx.x;
    bool hit = false; uint32_t u = 0;
    if (i < NN){
      u = fkey(p2[i].y);
      hit = (u >= thr);
    }
    uint32_t pos = wave_reserve(hit, &state[CNT_KEY(b)]);
    if (hit && pos < CAND_CAP)
      keys[(size_t)b*CAND_CAP + pos] = ((uint64_t)u << 32) | (uint32_t)(~(uint32_t)i);
  }
}

// ---- rank-sort: rank = #{keys > mine}; scatter id to sorted[rank] if rank < 6000 ----
__global__ __launch_bounds__(256) void k_rank(char* ws){
  __shared__ uint64_t tile[1024];
  uint32_t* state = (uint32_t*)ws;
  int b = blockIdx.y, t = threadIdx.x;
  uint32_t cnt = state[CNT_KEY(b)]; if (cnt > CAND_CAP) cnt = CAND_CAP;
  const uint64_t* kb = (const uint64_t*)(ws + OFF_KEY) + (size_t)b * CAND_CAP;
  uint32_t* sorted = (uint32_t*)(ws + OFF_SORTED);
  int kidx = blockIdx.x*256 + t;
  uint64_t my = (kidx < (int)cnt) ? kb[kidx] : 0ull;
  uint32_t r0 = 0, r1 = 0, r2 = 0, r3 = 0;
  for (int base = 0; base < CAND_CAP; base += 1024){
    for (int e = t; e < 1024; e += 256){
      int g = base + e;
      tile[e] = (g < (int)cnt) ? kb[g] : 0ull;
    }
    __syncthreads();
    int lim = (int)cnt - base; if (lim < 0) lim = 0; if (lim > 1024) lim = 1024;
    int lim4 = lim & ~3;
    for (int e = 0; e < lim4; e += 4){
      r0 += (tile[e]   > my) ? 1u : 0u;
      r1 += (tile[e+1] > my) ? 1u : 0u;
      r2 += (tile[e+2] > my) ? 1u : 0u;
      r3 += (tile[e+3] > my) ? 1u : 0u;
    }
    for (int e = lim4; e < lim; ++e) r0 += (tile[e] > my) ? 1u : 0u;
    __syncthreads();
  }
  uint32_t rank = r0 + r1 + r2 + r3;
  if (kidx < (int)cnt && rank < PRE_NMS){
    uint32_t id = ~(uint32_t)(my & 0xFFFFFFFFull);
    sorted[b*PRE_NMS + rank] = id;
  }
}

// ---- gather deltas/anchors at sorted ids, regress, clip ----
__global__ void k_gather(const float* __restrict__ boff, const float* __restrict__ anc, char* ws){
#pragma clang fp contract(off)
  int t = blockIdx.x*256 + threadIdx.x;
  if (t >= BATCH*PRE_NMS) return;
  int b = t / PRE_NMS, k = t - b*PRE_NMS;
  const uint32_t* sorted = (const uint32_t*)(ws + OFF_SORTED);
  float4* boxes = (float4*)(ws + OFF_BOXES);
  uint32_t id = sorted[b*PRE_NMS + k];
  float4 d4 = ((const float4*)boff)[(size_t)b*NN + id];
  float4 a4 = ((const float4*)anc )[(size_t)b*NN + id];
  float d0 = d4.x*0.1f, d1 = d4.y*0.1f, d2 = d4.z*0.2f, d3 = d4.w*0.2f;
  float h = a4.z - a4.x;
  float w = a4.w - a4.y;
  float cy = a4.x + 0.5f*h + d0*h;
  float cx = a4.y + 0.5f*w + d1*w;
  float h2 = h * expf(d2);
  float w2 = w * expf(d3);
  float y1 = cy - 0.5f*h2, x1 = cx - 0.5f*w2;
  float y2 = cy + 0.5f*h2, x2 = cx + 0.5f*w2;
  y1 = fminf(fmaxf(y1, 0.f), 1.f);
  x1 = fminf(fmaxf(x1, 0.f), 1.f);
  y2 = fminf(fmaxf(y2, 0.f), 1.f);
  x2 = fminf(fmaxf(x2, 0.f), 1.f);
  boxes[(size_t)b*NPAD + k] = make_float4(y1, x1, y2, x2);
}

// ---- spatial counting sort into 32x8 cells + per-64-box-tile bounds ----
__global__ __launch_bounds__(1024) void k_cellsort(char* ws){
  __shared__ uint32_t hist[256];
  __shared__ uint32_t cur[256];
  __shared__ uint16_t cell[PRE_NMS];
  int b = blockIdx.x, t = threadIdx.x;
  const float4* boxes = (const float4*)(ws + OFF_BOXES) + (size_t)b*NPAD;
  float4* sbox = (float4*)(ws + OFF_SBOX) + (size_t)b*NPAD;
  uint16_t* sorig = (uint16_t*)(ws + OFF_SORIG) + (size_t)b*NPAD;
  float* tmeta = (float*)(ws + OFF_TMETA) + (size_t)b*NTILE*6;
  if (t < 256) hist[t] = 0;
  __syncthreads();
  for (int k = t; k < PRE_NMS; k += 1024){
    float4 bx = boxes[k];
    float cy = 0.5f*(bx.x + bx.z), cx = 0.5f*(bx.y + bx.w);
    int iy = (int)(cy*32.f); iy = iy < 0 ? 0 : (iy > 31 ? 31 : iy);
    int ix = (int)(cx*8.f);  ix = ix < 0 ? 0 : (ix > 7 ? 7 : ix);
    int c = (iy << 3) | ix;
    cell[k] = (uint16_t)c;
    atomicAdd(&hist[c], 1u);
  }
  __syncthreads();
  if (t < 256) cur[t] = hist[t];
  __syncthreads();
  for (int d = 1; d < 256; d <<= 1){
    uint32_t v = 0;
    if (t < 256 && t >= d) v = cur[t - d];
    __syncthreads();
    if (t < 256) cur[t] += v;
    __syncthreads();
  }
  if (t < 256) cur[t] -= hist[t];
  __syncthreads();
  for (int k = t; k < PRE_NMS; k += 1024){
    uint32_t slot = atomicAdd(&cur[cell[k]], 1u);
    sbox[slot] = boxes[k];
    sorig[slot] = (uint16_t)k;
  }
  for (int k = PRE_NMS + t; k < NPAD; k += 1024){
    sbox[k] = make_float4(3.f, 3.f, 3.f, 3.f);   // far box, h=w=0 -> never hits
    sorig[k] = 0;
  }
  __syncthreads();
  int wid = t >> 6, lane = t & 63;
  for (int tt = wid; tt < NTILE; tt += 16){
    float4 bx = sbox[tt*64 + lane];
    float cy = 0.5f*(bx.x + bx.z), cx = 0.5f*(bx.y + bx.w);
    float h = bx.z - bx.x, w = bx.w - bx.y;
    float cymin = cy, cymax = cy, cxmin = cx, cxmax = cx, hmax = h, wmax = w;
    for (int d = 32; d >= 1; d >>= 1){
      cymin = fminf(cymin, __shfl_xor(cymin, d));
      cymax = fmaxf(cymax, __shfl_xor(cymax, d));
      cxmin = fminf(cxmin, __shfl_xor(cxmin, d));
      cxmax = fmaxf(cxmax, __shfl_xor(cxmax, d));
      hmax  = fmaxf(hmax,  __shfl_xor(hmax,  d));
      wmax  = fmaxf(wmax,  __shfl_xor(wmax,  d));
    }
    if (lane == 0){
      tmeta[tt*6+0] = cymin; tmeta[tt*6+1] = cymax;
      tmeta[tt*6+2] = cxmin; tmeta[tt*6+3] = cxmax;
      tmeta[tt*6+4] = hmax;  tmeta[tt*6+5] = wmax;
    }
  }
}

// ---- sparse edge build on spatially-ordered tiles with conservative pruning ----
__global__ __launch_bounds__(64) void k_edges(char* ws){
#pragma clang fp contract(off)
  const double M = 0x1.666667p-1;        // 0.7000000178813934326171875
  uint32_t* state = (uint32_t*)ws;
  const float4* sbox = (const float4*)(ws + OFF_SBOX);
  const uint16_t* sorig = (const uint16_t*)(ws + OFF_SORIG);
  const float* tmeta = (const float*)(ws + OFF_TMETA);
  uint32_t* edges = (uint32_t*)(ws + OFF_EDGES);
  int b = blockIdx.y, t = threadIdx.x;
  int p = blockIdx.x, ti = 0;
  while (p >= NTILE - ti){ p -= NTILE - ti; ++ti; }   // triangular decode (incl. diagonal)
  int tj = ti + p;
  const float* mi = tmeta + ((size_t)b*NTILE + ti)*6;
  const float* mj = tmeta + ((size_t)b*NTILE + tj)*6;
  float gapy = fmaxf(fmaxf(mj[0] - mi[1], mi[0] - mj[1]), 0.f);
  float gapx = fmaxf(fmaxf(mj[2] - mi[3], mi[2] - mj[3]), 0.f);
  float by = 0.3015f*fminf(mi[4], mj[4]) + 2e-5f;
  float bx = 0.3015f*fminf(mi[5], mj[5]) + 2e-5f;
  if (gapy >= by || gapx >= bx) return;               // uniform across block
  __shared__ float4 cb[64];
  __shared__ float  ca[64];
  __shared__ uint16_t co[64];
  int j0 = tj*64 + t;
  float4 bj0 = sbox[(size_t)b*NPAD + j0];
  cb[t] = bj0;
  ca[t] = (bj0.z - bj0.x)*(bj0.w - bj0.y);
  co[t] = sorig[(size_t)b*NPAD + j0];
  __syncthreads();
  int si = ti*64 + t;
  float4 bi = sbox[(size_t)b*NPAD + si];
  float ai = (bi.z - bi.x)*(bi.w - bi.y);
  uint32_t oi = sorig[(size_t)b*NPAD + si];
  uint64_t vm = (ti < tj) ? ~0ull : ((t == 63) ? 0ull : (~0ull << (t + 1)));
  uint64_t hitmask = 0;
#pragma unroll 8
  for (int jj = 0; jj < 64; ++jj){
    float4 bj = cb[jj];
    float yy1 = fmaxf(bi.x, bj.x);
    float xx1 = fmaxf(bi.y, bj.y);
    float yy2 = fminf(bi.z, bj.z);
    float xx2 = fminf(bi.w, bj.w);
    float ih = fmaxf(yy2 - yy1, 0.f);
    float iw = fmaxf(xx2 - xx1, 0.f);
    float inter = ih * iw;
    float uni = ai + ca[jj] - inter + 1e-9f;
    bool hit = (double)inter >= M * (double)uni;
    hitmask |= hit ? (1ull << jj) : 0ull;
  }
  hitmask &= vm;
  while (__any((int)(hitmask != 0ull))){
    bool pred = hitmask != 0ull;
    int jj = pred ? (__ffsll((unsigned long long)hitmask) - 1) : 0;
    uint32_t slot = wave_reserve(pred, &state[CNT_EDGE(b)]);
    if (pred && slot < EDGE_CAP){
      uint32_t oj = co[jj];
      uint32_t lo = oi < oj ? oi : oj;
      uint32_t hi = oi < oj ? oj : oi;
      edges[(size_t)b*EDGE_CAP + slot] = lo | (hi << 13);
    }
    hitmask &= hitmask - 1;
  }
}

// ---- greedy NMS sweep: window-bucketed edges (94 bins, not 6017-node CSR) ----
// Pass1/pass2 only ever consume offs[w*64]..offs[(w+1)*64] — i.e. per-window
// ranges — so bucket edges by source window directly: init 95 entries instead
// of 6017x3 strided passes (kills the 34.5K bank conflicts + 16 barriers).
// Box loads software-pipelined (prefetch w+1 during w).
__global__ __launch_bounds__(256) void k_scan(char* ws, float* __restrict__ out){
  __shared__ uint32_t ebuf[EDGE_CAP];      // (i&63)<<16 | j
  __shared__ uint32_t wdeg[NTILE + 1];
  __shared__ uint32_t woffs[NTILE + 1];
  __shared__ uint32_t wcur[NTILE];
  __shared__ uint32_t suppr[NW32];
  __shared__ uint32_t adjlo[64];
  __shared__ uint32_t adjhi[64];
  uint32_t* state = (uint32_t*)ws;
  const uint32_t* eb = (const uint32_t*)(ws + OFF_EDGES) + (size_t)blockIdx.x * EDGE_CAP;
  const float4* boxes = (const float4*)(ws + OFF_BOXES);
  int b = blockIdx.x, t = threadIdx.x;

  if (t <= NTILE) wdeg[t] = 0;
  for (int i = t; i < NW32; i += 256) suppr[i] = 0;
  __syncthreads();
  uint32_t E = state[CNT_EDGE(b)]; if (E > EDGE_CAP) E = EDGE_CAP;
  for (uint32_t e = t; e < E; e += 256)
    atomicAdd(&wdeg[(eb[e] & 0x1FFFu) >> 6], 1u);
  __syncthreads();
  // inclusive scan over NTILE+1 entries (Hillis-Steele), then exclusive
  if (t <= NTILE) woffs[t] = wdeg[t];
  __syncthreads();
  for (int d = 1; d <= NTILE; d <<= 1){
    uint32_t v = 0;
    if (t <= NTILE && t >= d) v = woffs[t - d];
    __syncthreads();
    if (t <= NTILE) woffs[t] += v;
    __syncthreads();
  }
  if (t <= NTILE){
    uint32_t ex = woffs[t] - wdeg[t];
    woffs[t] = ex;
    if (t < NTILE) wcur[t] = ex;
  }
  __syncthreads();
  for (uint32_t e = t; e < E; e += 256){
    uint32_t ed = eb[e];
    uint32_t ii = ed & 0x1FFFu, jj = ed >> 13;
    uint32_t slot = atomicAdd(&wcur[ii >> 6], 1u);
    ebuf[slot] = ((ii & 63u) << 16) | jj;
  }
  __syncthreads();
  if (t >= 64) return;                     // serial phase: wave 0 only
  int lane = t;
  uint32_t nsel = 0;
  float4 nbox = boxes[(size_t)b*NPAD + lane];       // prefetch window 0
  for (int w = 0; w < NTILE && nsel < NUM_PROP; ++w){
    int base = w*64;
    float4 mybox = nbox;
    if (w + 1 < NTILE) nbox = boxes[(size_t)b*NPAD + base + 64 + lane];  // prefetch next
    adjlo[lane] = 0; adjhi[lane] = 0;
    uint64_t sup = (uint64_t)suppr[2*w] | ((uint64_t)suppr[2*w + 1] << 32);
    uint64_t live = ~sup;
    int valid = PRE_NMS - base;
    if (valid < 64) live &= ((1ull << valid) - 1ull);
    uint32_t r0 = woffs[w], r1 = woffs[w + 1];
    bool anyIn = false;
    for (uint32_t idx = r0 + (uint32_t)lane; idx < r1; idx += 64){
      uint32_t e = ebuf[idx];
      uint32_t il = e >> 16, j = e & 0xFFFFu;
      if (((live >> il) & 1ull) && j < (uint32_t)(base + 64)){
        uint32_t l2 = j - (uint32_t)base;
        if (l2 < 32) atomicOr(&adjlo[il], 1u << l2);
        else         atomicOr(&adjhi[il], 1u << (l2 - 32));
        anyIn = true;
      }
    }
    anyIn = __any((int)anyIn);
    uint64_t sel;
    if (!anyIn){
      uint32_t cnt = __popcll(live);
      uint32_t remn = NUM_PROP - nsel;
      uint32_t take = cnt < remn ? cnt : remn;
      if (live & (1ull << lane)){
        uint32_t r = __popcll(live & ((1ull << lane) - 1ull));
        if (r < take) ((float4*)out)[(size_t)b*NUM_PROP + nsel + r] = mybox;
      }
      nsel += take;
      sel = live;
    } else {
      uint64_t row = (uint64_t)adjlo[lane] | ((uint64_t)adjhi[lane] << 32);
      uint64_t m = live;
      sel = 0;
      while (m && nsel < NUM_PROP){
        int f = __ffsll((unsigned long long)m) - 1;
        m &= m - 1;
        sel |= 1ull << f;
        if (lane == f) ((float4*)out)[(size_t)b*NUM_PROP + nsel] = mybox;
        nsel++;
        m &= ~shfl64(row, f);
      }
    }
    if (nsel >= NUM_PROP) break;
    for (uint32_t idx = r0 + (uint32_t)lane; idx < r1; idx += 64){
      uint32_t e = ebuf[idx];
      uint32_t il = e >> 16, j = e & 0xFFFFu;
      if (((sel >> il) & 1ull) && j >= (uint32_t)(base + 64))
        atomicOr(&suppr[j >> 5], 1u << (j & 31));
    }
  }
  for (uint32_t r = nsel + (uint32_t)lane; r < NUM_PROP; r += 64)
    ((float4*)out)[(size_t)b*NUM_PROP + r] = make_float4(0.f, 0.f, 0.f, 0.f);
}

extern "C" void kernel_launch(void* const* d_in, const int* in_sizes, int n_in,
                              void* d_out, int out_size, void* d_ws, size_t ws_size,
                              hipStream_t stream){
  const float* probs = (const float*)d_in[0];
  const float* boff  = (const float*)d_in[1];
  const float* anc   = (const float*)d_in[2];
  char* ws = (char*)d_ws;
  float* out = (float*)d_out;

  hipMemsetAsync(ws, 0, OFF_KEY, stream);  // zero state + both histograms
  k_hist1   <<<dim3(128, BATCH), 256, 0, stream>>>(probs, ws);
  k_resolve <<<BATCH, 256, 0, stream>>>(ws, 1);
  k_hist2   <<<dim3(128, BATCH), 256, 0, stream>>>(probs, ws);
  k_resolve <<<BATCH, 256, 0, stream>>>(ws, 2);
  k_compact <<<dim3(128, BATCH), 256, 0, stream>>>(probs, ws);
  k_rank    <<<dim3(CAND_CAP/256, BATCH), 256, 0, stream>>>(ws);
  k_gather  <<<(BATCH*PRE_NMS + 255)/256, 256, 0, stream>>>(boff, anc, ws);
  k_cellsort<<<BATCH, 1024, 0, stream>>>(ws);
  k_edges   <<<dim3(NTILE*(NTILE+1)/2, BATCH), 64, 0, stream>>>(ws);
  k_scan    <<<BATCH, 256, 0, stream>>>(ws, out);
}